// Round 7
// baseline (495.058 us; speedup 1.0000x reference)
//
#include <hip/hip_runtime.h>
#include <hip/hip_bf16.h>
#include <cstdint>

// SpatialAttentionModule: x[4,256,64,64] fp32; q=Wq x, k=Wk x, v=Wv x (1x1 conv);
// energy = q^T k per batch (N=4096), softmax over j, out = gamma*(v@attn^T) + x.
//
// Round-7: fat waves. R4-R6 all plateau at ~180-193us because 16-query waves
// force every resident wave to re-read full K/V tiles -> LDS-pipe floor
// ~90-110us regardless of barriers/occupancy. This round: 32-query waves with
// mfma_f32_32x32x16_f16 (halves fragment bytes and softmax VALU per q*k).
// Block = 64 queries, 4 waves; keys split x2 inside the block (waves 0,2 take
// even 32-key tiles, 1,3 odd) each with private online-softmax state (m,l,O),
// merged exactly at the end (flash merge) via LDS. One barrier per period;
// K/V staged by wave-role DMA (w0:K-even w1:V-even w2:K-odd w3:V-odd).
// MFMA 32x32x16 layouts (C/D verified m74/m101; A/B natural extension of the
// m89-verified 16x16 mapping): A[m=lane&31][k=(lane>>5)*8+j],
// B[k=(lane>>5)*8+j][n=lane&31], C/D: col=lane&31, row=(reg&3)+8*(reg>>2)+4*(lane>>5).

#define C_DIM 256
#define N_DIM 4096
#define B_DIM 4

typedef _Float16 f16;
typedef f16 f16x8 __attribute__((ext_vector_type(8)));
typedef f16 f16x4 __attribute__((ext_vector_type(4)));
typedef float f32x4 __attribute__((ext_vector_type(4)));
typedef float f32x16 __attribute__((ext_vector_type(16)));

__device__ __forceinline__ void dma16(const f16* g, f16* l) {
  __builtin_amdgcn_global_load_lds(
      (const __attribute__((address_space(1))) unsigned int*)g,
      (__attribute__((address_space(3))) unsigned int*)l, 16, 0, 0);
}

// ---------------- prep: transpose-cast x -> xs fp16 [B*N][256] ----------------
__global__ __launch_bounds__(256) void k_prep_xs(const float* __restrict__ x,
                                                 f16* __restrict__ xs) {
  __shared__ float tile[64][65];
  const int b = blockIdx.z, nb = blockIdx.x * 64, cb = blockIdx.y * 64;
  const float* xb = x + (size_t)b * C_DIM * N_DIM;
  for (int i = threadIdx.x; i < 64 * 64; i += 256) {
    int c = i >> 6, n = i & 63;
    tile[c][n] = xb[(size_t)(cb + c) * N_DIM + nb + n];
  }
  __syncthreads();
  f16* xsb = xs + (size_t)b * N_DIM * C_DIM;
  for (int i = threadIdx.x; i < 64 * 64; i += 256) {
    int n = i >> 6, c = i & 63;
    xsb[(size_t)(nb + n) * C_DIM + cb + c] = (f16)tile[c][n];
  }
}

// ---------------- prep: cast 3 weight matrices -> fp16 [3*256][256] ----------------
__global__ __launch_bounds__(256) void k_cast_w(const float* __restrict__ Wq,
                                                const float* __restrict__ Wk,
                                                const float* __restrict__ Wv,
                                                f16* __restrict__ Wh) {
  int i = blockIdx.x * 256 + threadIdx.x;
  int sel = i >> 16, j = i & 65535;
  const float* s = (sel == 0) ? Wq : (sel == 1) ? Wk : Wv;
  Wh[i] = (f16)s[j];
}

// ---------------- QKV projection GEMMs (fp16, K=256) ----------------
__global__ __launch_bounds__(256) void k_proj(const f16* __restrict__ xs,
                                              const f16* __restrict__ Wh,
                                              const float* __restrict__ bq,
                                              const float* __restrict__ bk,
                                              const float* __restrict__ bv,
                                              f16* __restrict__ Qh,
                                              f16* __restrict__ Kh,
                                              f16* __restrict__ Vh) {
  const int z = blockIdx.y;
  const int w = threadIdx.x >> 6, lane = threadIdx.x & 63;
  const int quad = lane >> 4, li = lane & 15;
  const f16* W = Wh + (size_t)z * 65536;
  const float* bias = (z == 0) ? bq : (z == 1) ? bk : bv;

  if (z < 2) {
    f16* out = (z == 0) ? Qh : Kh;
    const int g0 = (blockIdx.x * 4 + w) * 16;
    f16x8 a[8];
    const f16* arow = xs + (size_t)(g0 + li) * C_DIM + quad * 8;
#pragma unroll
    for (int kf = 0; kf < 8; kf++) a[kf] = *(const f16x8*)(arow + kf * 32);
    for (int ot = 0; ot < 16; ot++) {
      f32x4 acc = {0.f, 0.f, 0.f, 0.f};
      const f16* brow = W + (size_t)(ot * 16 + li) * C_DIM + quad * 8;
#pragma unroll
      for (int kf = 0; kf < 8; kf++) {
        f16x8 bf = *(const f16x8*)(brow + kf * 32);
        acc = __builtin_amdgcn_mfma_f32_16x16x32_f16(a[kf], bf, acc, 0, 0, 0);
      }
      float bb = bias[ot * 16 + li];
      f16* orow = out + (size_t)g0 * C_DIM + ot * 16 + li;
#pragma unroll
      for (int r = 0; r < 4; r++)
        orow[(size_t)(quad * 4 + r) * C_DIM] = (f16)(acc[r] + bb);
    }
  } else {
    const int t = blockIdx.x * 4 + w;
    const int b = t >> 8, j0 = (t & 255) * 16;
    f16x8 bfr[8];
    const f16* brow = xs + (size_t)(b * N_DIM + j0 + li) * C_DIM + quad * 8;
#pragma unroll
    for (int kf = 0; kf < 8; kf++) bfr[kf] = *(const f16x8*)(brow + kf * 32);
    for (int ot = 0; ot < 16; ot++) {
      f32x4 acc = {0.f, 0.f, 0.f, 0.f};
      const f16* arow = W + (size_t)(ot * 16 + li) * C_DIM + quad * 8;
#pragma unroll
      for (int kf = 0; kf < 8; kf++) {
        f16x8 af = *(const f16x8*)(arow + kf * 32);
        acc = __builtin_amdgcn_mfma_f32_16x16x32_f16(af, bfr[kf], acc, 0, 0, 0);
      }
      f16* obase = Vh + ((size_t)(b * C_DIM + ot * 16 + quad * 4)) * N_DIM + j0 + li;
#pragma unroll
      for (int r = 0; r < 4; r++) {
        float bb = bias[ot * 16 + quad * 4 + r];
        obase[(size_t)r * N_DIM] = (f16)(acc[r] + bb);
      }
    }
  }
}

// ---------------- fused attention ----------------
// grid (64,4): 64-query block, batch; 4 waves; 1 block/CU.
// Wave w: queries (w>>1)*32..+32, key tiles 2u+(w&1) (32 keys each), u=0..63.
// Staging role: sp=w>>1 (tile parity), kind=w&1 (0=K,1=V): 16 dma16/wave/period.
// LDS (f16 units):
//   K bufs [par][db]: 16 pairs x 528: phys(r,ch) = (r>>1)*528 + (r&1)*256 + ch
//   V bufs [par][db]: 16 grps x 528: phys(c,j)  = (c>>4)*528 + (c&15)*32 + j
//   P per wave: [32 q][PSTR=40]
//   merge: reuses K/V area as float scratch after the loop.
#define JT 32
#define NPER 64
#define KB_OFF 0            // 4 x 8448
#define VB_OFF 33792        // 4 x 8448
#define P_OFF  67584        // 4 x 1280
#define PSTR 40
#define SMEM_F16 72704      // 145,408 B

__global__ __launch_bounds__(256, 1) void k_attn(const f16* __restrict__ Qh,
                                                 const f16* __restrict__ Kh,
                                                 const f16* __restrict__ Vh,
                                                 const float* __restrict__ x,
                                                 const float* __restrict__ gamma_p,
                                                 float* __restrict__ out) {
  __shared__ __align__(16) f16 smem[SMEM_F16];
  const int b = blockIdx.y;
  const int tid = threadIdx.x;
  const int w = tid >> 6, lane = tid & 63;
  const int cq = lane & 31;          // query col (compute) / key (A-frag read)
  const int h = lane >> 5;
  const int qs = w >> 1, par = w & 1;
  const int sp = w >> 1, kind = w & 1;   // staging role
  const int q0 = blockIdx.x * 64;

  const f16* Kb = Kh + (size_t)b * N_DIM * C_DIM;
  const f16* Vb = Vh + (size_t)b * C_DIM * N_DIM;
  f16* Pw = smem + P_OFF + w * 1280;

  // Q B-frags: 32 queries x 256 ch (held in registers)
  f16x8 qf[16];
  {
    const f16* qrow = Qh + (size_t)(b * N_DIM + q0 + qs * 32 + cq) * C_DIM + h * 8;
#pragma unroll
    for (int c = 0; c < 16; c++) qf[c] = *(const f16x8*)(qrow + c * 16);
  }

  float m = -3.0e38f, l_lane = 0.0f;
  f32x16 acc[8];
#pragma unroll
  for (int ct = 0; ct < 8; ct++) acc[ct] = (f32x16){};

  // prologue: stage period-0 (tiles 0 and 1) into db=0
  {
    const int kt = sp * JT;
    if (kind == 0) {
      f16* dst = smem + KB_OFF + (sp * 2 + 0) * 8448;
      const int c8 = (lane & 31) * 8;
#pragma unroll
      for (int i = 0; i < 16; i++)
        dma16(Kb + (size_t)(kt + 2 * i + h) * C_DIM + c8, dst + i * 528);
    } else {
      f16* dst = smem + VB_OFF + (sp * 2 + 0) * 8448;
#pragma unroll
      for (int i = 0; i < 16; i++)
        dma16(Vb + (size_t)(i * 16 + (lane >> 2)) * N_DIM + kt + (lane & 3) * 8,
              dst + i * 528);
    }
  }
  __syncthreads();

  for (int u = 0; u < NPER; u++) {
    const int db = u & 1;
    const f16* Kc = smem + KB_OFF + (par * 2 + db) * 8448;
    const f16* Vc = smem + VB_OFF + (par * 2 + db) * 8448;

    // ---- S: 32 keys x 32 queries, K=256 (two independent 8-chains) ----
    f32x16 s0 = (f32x16){}, s1 = (f32x16){};
    {
      const f16* ka = Kc + (cq >> 1) * 528 + (cq & 1) * 256 + h * 8;
#pragma unroll
      for (int c = 0; c < 8; c++)
        s0 = __builtin_amdgcn_mfma_f32_32x32x16_f16(*(const f16x8*)(ka + c * 16),
                                                    qf[c], s0, 0, 0, 0);
#pragma unroll
      for (int c = 8; c < 16; c++)
        s1 = __builtin_amdgcn_mfma_f32_32x32x16_f16(*(const f16x8*)(ka + c * 16),
                                                    qf[c], s1, 0, 0, 0);
    }
    f32x16 s = s0 + s1;

    // ---- staging for period u+1 (issued early; drained at the barrier) ----
    if (u + 1 < NPER) {
      const int db2 = db ^ 1;
      const int kt = (2 * (u + 1) + sp) * JT;
      if (kind == 0) {
        f16* dst = smem + KB_OFF + (sp * 2 + db2) * 8448;
        const int c8 = (lane & 31) * 8;
#pragma unroll
        for (int i = 0; i < 16; i++)
          dma16(Kb + (size_t)(kt + 2 * i + h) * C_DIM + c8, dst + i * 528);
      } else {
        f16* dst = smem + VB_OFF + (sp * 2 + db2) * 8448;
#pragma unroll
        for (int i = 0; i < 16; i++)
          dma16(Vb + (size_t)(i * 16 + (lane >> 2)) * N_DIM + kt + (lane & 3) * 8,
                dst + i * 528);
      }
    }

    // ---- wave-local online softmax (per query col cq) ----
    float tm = s[0];
#pragma unroll
    for (int i = 1; i < 16; i++) tm = fmaxf(tm, s[i]);
    tm = fmaxf(tm, __shfl_xor(tm, 32));
    float nm = fmaxf(m, tm);
    float al = __expf(m - nm);
    bool upd = nm > m;
    m = nm;
    if (__any(upd)) {
      l_lane *= al;
#pragma unroll
      for (int ct = 0; ct < 8; ct++) acc[ct] *= al;
    }
    float lsum = 0.0f;
#pragma unroll
    for (int rq = 0; rq < 4; rq++) {
      float p0 = __expf(s[rq * 4 + 0] - m);
      float p1 = __expf(s[rq * 4 + 1] - m);
      float p2 = __expf(s[rq * 4 + 2] - m);
      float p3 = __expf(s[rq * 4 + 3] - m);
      lsum += (p0 + p1) + (p2 + p3);
      // keys rq*8 + 4h + {0..3} for query cq
      *(f16x4*)(Pw + cq * PSTR + rq * 8 + 4 * h) =
          (f16x4){(f16)p0, (f16)p1, (f16)p2, (f16)p3};
    }
    l_lane += lsum;

    // ---- PV: O[ch 256][q 32] += V[ch][k 32] P[k][q] ----
    f16x8 pf0 = *(const f16x8*)(Pw + cq * PSTR + h * 8);        // keys 0..15
    f16x8 pf1 = *(const f16x8*)(Pw + cq * PSTR + 16 + h * 8);   // keys 16..31
#pragma unroll
    for (int ct = 0; ct < 8; ct++) {
      const f16* va = Vc + (ct * 2 + (cq >> 4)) * 528 + (cq & 15) * 32 + h * 8;
      acc[ct] = __builtin_amdgcn_mfma_f32_32x32x16_f16(*(const f16x8*)(va), pf0,
                                                       acc[ct], 0, 0, 0);
      acc[ct] = __builtin_amdgcn_mfma_f32_32x32x16_f16(*(const f16x8*)(va + 16), pf1,
                                                       acc[ct], 0, 0, 0);
    }

    __syncthreads();   // buf swap + DMA drain
  }

  // ---- flash merge between key-parity partner waves (w ^ 1) ----
  l_lane += __shfl_xor(l_lane, 32);   // fold row-halves: l per query col
  float* xch = (float*)smem;          // reuse K/V area (safe after barrier)
  float* mlx = xch + 16384;           // 4 KB of m/l slots
  {
    // send the half of channels the partner will own
    const int sct0 = (w & 1) ? 0 : 4;
    float* myr = xch + w * 4096;
#pragma unroll
    for (int t2 = 0; t2 < 4; t2++)
#pragma unroll
      for (int i = 0; i < 8; i++)
        *(float2*)(myr + (t2 * 8 + i) * 128 + lane * 2) =
            make_float2(acc[sct0 + t2][2 * i], acc[sct0 + t2][2 * i + 1]);
    mlx[w * 128 + lane] = m;
    mlx[512 + w * 128 + lane] = l_lane;
  }
  __syncthreads();
  const int partner = w ^ 1;
  const int kct0 = (w & 1) ? 4 : 0;   // channel tiles this wave keeps & stores
  float mp = mlx[partner * 128 + lane];
  float lp = mlx[512 + partner * 128 + lane];
  float ms = fmaxf(m, mp);
  float a0 = __expf(m - ms), a1 = __expf(mp - ms);
  float ls = a0 * l_lane + a1 * lp;
  const float scale = gamma_p[0] / ls;
  const float* pr = xch + partner * 4096;

  const float* xb = x + (size_t)b * C_DIM * N_DIM;
  float* ob = out + (size_t)b * C_DIM * N_DIM;
  const int qcol = q0 + qs * 32 + cq;
#pragma unroll
  for (int t2 = 0; t2 < 4; t2++) {
    const int ct = kct0 + t2;
#pragma unroll
    for (int i = 0; i < 8; i++) {
      float2 o = *(const float2*)(pr + (t2 * 8 + i) * 128 + lane * 2);
      float v0 = a0 * acc[ct][2 * i] + a1 * o.x;
      float v1 = a0 * acc[ct][2 * i + 1] + a1 * o.y;
      int r0 = 2 * i, r1 = 2 * i + 1;
      int ch0 = ct * 32 + (r0 & 3) + 8 * (r0 >> 2) + 4 * h;
      int ch1 = ct * 32 + (r1 & 3) + 8 * (r1 >> 2) + 4 * h;
      size_t off0 = (size_t)ch0 * N_DIM + qcol;
      size_t off1 = (size_t)ch1 * N_DIM + qcol;
      ob[off0] = v0 * scale + xb[off0];
      ob[off1] = v1 * scale + xb[off1];
    }
  }
}

extern "C" void kernel_launch(void* const* d_in, const int* in_sizes, int n_in,
                              void* d_out, int out_size, void* d_ws, size_t ws_size,
                              hipStream_t stream) {
  const float* x     = (const float*)d_in[0];
  const float* Wq    = (const float*)d_in[1];
  const float* bq    = (const float*)d_in[2];
  const float* Wk    = (const float*)d_in[3];
  const float* bk    = (const float*)d_in[4];
  const float* Wv    = (const float*)d_in[5];
  const float* bv    = (const float*)d_in[6];
  const float* gamma = (const float*)d_in[7];
  float* out = (float*)d_out;

  // workspace: xs 8MB | Qh 8MB | Kh 8MB | Vh 8MB | Wh 384KB  (~32.4 MB)
  char* ws = (char*)d_ws;
  f16* xs = (f16*)(ws);
  f16* Qh = (f16*)(ws + (size_t)8  * 1024 * 1024);
  f16* Kh = (f16*)(ws + (size_t)16 * 1024 * 1024);
  f16* Vh = (f16*)(ws + (size_t)24 * 1024 * 1024);
  f16* Wh = (f16*)(ws + (size_t)32 * 1024 * 1024);

  k_prep_xs<<<dim3(64, 4, 4), 256, 0, stream>>>(x, xs);
  k_cast_w<<<dim3(768), 256, 0, stream>>>(Wq, Wk, Wv, Wh);
  k_proj<<<dim3(256, 3), 256, 0, stream>>>(xs, Wh, bq, bk, bv, Qh, Kh, Vh);
  k_attn<<<dim3(64, 4), 256, 0, stream>>>(Qh, Kh, Vh, x, gamma, out);
}